// Round 11
// baseline (243.008 us; speedup 1.0000x reference)
//
#include <hip/hip_runtime.h>
#include <hip/hip_bf16.h>

typedef __hip_bfloat16 bf16;
typedef __attribute__((ext_vector_type(8))) unsigned short u16x8;
typedef __attribute__((ext_vector_type(8))) short s16x8;
typedef __attribute__((ext_vector_type(4))) float f32x4;
typedef __attribute__((ext_vector_type(4))) unsigned short us16x4;

#define B_   4
#define C_   32
#define DW_  64
#define H_   256
#define W_   256
#define P_   65536          // H_*W_
#define SRC_ 32             // source filter grid 32x32
#define TRS_ 272            // t1 padded row stride in shorts (544 B = 34*16, keeps 16B align)
#define TPL_ 70176          // padded plane shorts: 258 rows * 272

// ---- ws layout (float indices for the small stuff) ----
#define OW1    0            // 64*32
#define OB1    2048         // 64
#define OW3    2112         // 32*32
#define OB3    3136         // 32
#define OWS    3168         // 32*32 (sca)
#define OBS    4192         // 32
#define OW4    4224         // 64*32
#define OB4    6272         // 64
#define OW5    6336         // 32*32
#define OB5    7360         // 32
#define ON1W   7392
#define ON1B   7424
#define ON2W   7456
#define ON2B   7488
#define OBETA  7520
#define OGAMMA 7552
#define OSUMS  7584         // B_*C_ = 128
#define OSVEC  7712         // B_*C_ = 128 (unused now, kept for layout stability)
#define OFLAG  7900         // int flag: 0 = fp32 inputs, 1 = bf16 inputs
// byte offsets for big intermediates
#define CWF_BOFF 32768ull                        // cwfT fp32: 4*1024*576*4 = 9437184 B
#define T1_BOFF  (CWF_BOFF + 9437184ull)         // t1 padded bf16: 256*70176*2 = 35930112 B
#define G_BOFF   (T1_BOFF + 35930112ull)         // g bf16: 16777216 B
// total ws ~= 62.2 MB

__device__ __forceinline__ bf16  f2b(float v){ return __float2bfloat16(v); }
__device__ __forceinline__ float bfu(unsigned short u){ return __uint_as_float(((unsigned int)u) << 16); }
__device__ __forceinline__ unsigned short fbits(float v){
    bf16 b = __float2bfloat16(v);
    return *reinterpret_cast<unsigned short*>(&b);
}

template<typename T> __device__ __forceinline__ float ldf(const T* p);
template<> __device__ __forceinline__ float ldf<float>(const float* p){ return *p; }
template<> __device__ __forceinline__ float ldf<bf16>(const bf16* p){ return __bfloat162float(*p); }

template<typename T> struct dtag;
template<> struct dtag<float>{ static constexpr int v = 0; };
template<> struct dtag<bf16>{ static constexpr int v = 1; };

__device__ __forceinline__ f32x4 MF(s16x8 a, s16x8 b, f32x4 c){
    return __builtin_amdgcn_mfma_f32_16x16x32_bf16(a, b, c, 0, 0, 0);
}
// 8 consecutive fp32 weights -> bf16x8 fragment
__device__ __forceinline__ s16x8 wfrag8(const float* p){
    float4 a = *(const float4*)p;
    float4 c = *(const float4*)(p + 4);
    s16x8 r;
    r[0] = (short)fbits(a.x); r[1] = (short)fbits(a.y);
    r[2] = (short)fbits(a.z); r[3] = (short)fbits(a.w);
    r[4] = (short)fbits(c.x); r[5] = (short)fbits(c.y);
    r[6] = (short)fbits(c.z); r[7] = (short)fbits(c.w);
    return r;
}

// ---------------- dtype detector (fp32 low-mantissa halves decode huge/NaN) ----------------
__global__ void k_detect(const unsigned short* __restrict__ raw, int* __restrict__ flag)
{
    int t = threadIdx.x;  // 64 threads
    int bad = 0;
    for (int k = 0; k < 8; ++k) {
        unsigned short u = raw[2 * (t + 64 * k)];
        float v = __uint_as_float(((unsigned int)u) << 16);
        if (!(fabsf(v) < 1e6f)) bad = 1;
    }
    int anybad = __any(bad);
    if (t == 0) *flag = anybad ? 0 : 1;
}

// ---------------- weights -> fp32 in ws, zero SCA sums ----------------
template<typename T>
__global__ void k_prep(const T* __restrict__ w1, const T* __restrict__ b1,
                       const T* __restrict__ w3, const T* __restrict__ b3,
                       const T* __restrict__ wsc, const T* __restrict__ bsc_,
                       const T* __restrict__ w4, const T* __restrict__ b4,
                       const T* __restrict__ w5, const T* __restrict__ b5,
                       const T* __restrict__ n1w, const T* __restrict__ n1b,
                       const T* __restrict__ n2w, const T* __restrict__ n2b,
                       const T* __restrict__ bet, const T* __restrict__ gam,
                       float* __restrict__ wsf, const int* __restrict__ flag)
{
    if (*flag != dtag<T>::v) return;
    int t = threadIdx.x;
    for (int i = t; i < 2048; i += 256) wsf[OW1 + i] = ldf<T>(w1 + i);
    for (int i = t; i < 64;   i += 256) wsf[OB1 + i] = ldf<T>(b1 + i);
    for (int i = t; i < 1024; i += 256) wsf[OW3 + i] = ldf<T>(w3 + i);
    for (int i = t; i < 32;   i += 256) wsf[OB3 + i] = ldf<T>(b3 + i);
    for (int i = t; i < 1024; i += 256) wsf[OWS + i] = ldf<T>(wsc + i);
    for (int i = t; i < 32;   i += 256) wsf[OBS + i] = ldf<T>(bsc_ + i);
    for (int i = t; i < 2048; i += 256) wsf[OW4 + i] = ldf<T>(w4 + i);
    for (int i = t; i < 64;   i += 256) wsf[OB4 + i] = ldf<T>(b4 + i);
    for (int i = t; i < 1024; i += 256) wsf[OW5 + i] = ldf<T>(w5 + i);
    for (int i = t; i < 32;   i += 256) wsf[OB5 + i] = ldf<T>(b5 + i);
    for (int i = t; i < 32;   i += 256) wsf[ON1W + i] = ldf<T>(n1w + i);
    for (int i = t; i < 32;   i += 256) wsf[ON1B + i] = ldf<T>(n1b + i);
    for (int i = t; i < 32;   i += 256) wsf[ON2W + i] = ldf<T>(n2w + i);
    for (int i = t; i < 32;   i += 256) wsf[ON2B + i] = ldf<T>(n2b + i);
    for (int i = t; i < 32;   i += 256) wsf[OBETA + i] = ldf<T>(bet + i);
    for (int i = t; i < 32;   i += 256) wsf[OGAMMA + i] = ldf<T>(gam + i);
    for (int i = t; i < 128;  i += 256) wsf[OSUMS + i] = 0.f;
}

// ------- cw2 -> cwfT[b][rc][tap][p] via LDS-tiled transpose (both sides coalesced) -------
// p = [cg 3][chq 1][ch4 2] bits; oc = chq*32 + cg*4 + ch4. 576 blocks: b(4) x tap(9) x rct(16).
__global__ __launch_bounds__(256) void k_cwf(const void* __restrict__ cw,
        float* __restrict__ cwfT, const int* __restrict__ flag)
{
    __shared__ float tile[64][65];
    int blk = blockIdx.x;
    int rct = blk & 15;
    int tap = (blk >> 4) % 9;
    int b   = blk / 144;
    int rc0 = rct * 64;
    int tl  = threadIdx.x & 63;
    int tg  = threadIdx.x >> 6;
    int fl  = *flag;
    #pragma unroll
    for (int it = 0; it < 16; ++it) {
        int oc = it * 4 + tg;
        size_t iidx = ((size_t)(b * DW_ + oc) * 9 + tap) * 1024 + rc0 + tl;
        tile[oc][tl] = (fl == 0) ? ((const float*)cw)[iidx]
                                 : bfu(((const unsigned short*)cw)[iidx]);
    }
    __syncthreads();
    #pragma unroll
    for (int it = 0; it < 16; ++it) {
        int rcl = it * 4 + tg;
        int p = tl;
        int oc = ((p >> 2) & 1) * 32 + (p >> 3) * 4 + (p & 3);
        cwfT[((size_t)(b * 1024 + rc0 + rcl) * 9 + tap) * 64 + p] = tile[oc][rcl];
    }
}

// ------- LN1 + conv1 v3 (MFMA + LDS-transposed full-row stores) -------
#define OSTR1_ 280
template<typename T>
__device__ __forceinline__ void ln1_body(const T* __restrict__ inp,
        const float* __restrict__ wsf, bf16* __restrict__ t1p,
        short* __restrict__ xsh, short* __restrict__ osh)
{
    const int t = threadIdx.x;
    const int b = blockIdx.x >> 8;
    const int h = blockIdx.x & 255;
    const int p0 = h << 8;

    {
        const T* ip = inp + (size_t)(b * C_) * P_ + p0 + t;
        float v[C_];
        float m = 0.f;
        #pragma unroll
        for (int ch = 0; ch < C_; ++ch) { v[ch] = ldf<T>(ip + (size_t)ch * P_); m += v[ch]; }
        m *= (1.f / C_);
        float var = 0.f;
        #pragma unroll
        for (int ch = 0; ch < C_; ++ch) { float d = v[ch] - m; var += d * d; }
        var *= (1.f / C_);
        float inv = rsqrtf(var + 1e-6f);
        u16x8* xr = (u16x8*)(xsh + t * 32);
        #pragma unroll
        for (int qq = 0; qq < 4; ++qq) {
            u16x8 vv;
            #pragma unroll
            for (int j = 0; j < 8; ++j) {
                int ch = qq * 8 + j;
                vv[j] = fbits((v[ch] - m) * inv * wsf[ON1W + ch] + wsf[ON1B + ch]);
            }
            xr[qq] = vv;
        }
        int och = t >> 4, cc = t & 15;
        osh[och * OSTR1_ + (cc == 0 ? 0 : 256 + cc)] = 0;
    }
    __syncthreads();

    const int lane = t & 63, wv = t >> 6;
    const int l15 = lane & 15, l4 = lane >> 4;
    const int wp0 = wv * 64;

    s16x8 w1f[4];
    f32x4 b1v[4];
    #pragma unroll
    for (int m = 0; m < 4; ++m) {
        w1f[m] = wfrag8(wsf + OW1 + (m * 16 + l15) * 32 + l4 * 8);
        b1v[m] = *(const f32x4*)(wsf + OB1 + m * 16 + l4 * 4);
    }
    s16x8 xb[4];
    #pragma unroll
    for (int tn = 0; tn < 4; ++tn)
        xb[tn] = *(const s16x8*)(xsh + (wp0 + tn * 16 + l15) * 32 + l4 * 8);

    const size_t prow = (size_t)(b * DW_) * TPL_ + (size_t)(h + 1) * TRS_;
    #pragma unroll
    for (int m = 0; m < 4; ++m) {
        #pragma unroll
        for (int tn = 0; tn < 4; ++tn) {
            f32x4 acc = MF(w1f[m], xb[tn], b1v[m]);
            int px = wp0 + tn * 16 + l15;
            #pragma unroll
            for (int i = 0; i < 4; ++i)
                osh[(l4 * 4 + i) * OSTR1_ + 1 + px] = (short)fbits(acc[i]);
        }
        __syncthreads();
        for (int it = 0; it < 3; ++it) {
            int idx = it * 256 + t;
            if (idx < 544) {
                int och = idx / 34, ck = idx - och * 34;
                u16x8 v = *(const u16x8*)(osh + och * OSTR1_ + ck * 8);
                *(u16x8*)((unsigned short*)t1p + prow + (size_t)(m * 16 + och) * TPL_ + ck * 8) = v;
            }
        }
        __syncthreads();
    }

    if (h == 0 || h == 255) {
        size_t rbase = (size_t)(b * DW_) * TPL_ + (h == 0 ? 0 : (size_t)257 * TRS_);
        u16x8 z;
        #pragma unroll
        for (int j = 0; j < 8; ++j) z[j] = 0;
        for (int it = 0; it < 9; ++it) {
            int idx = it * 256 + t;
            if (idx < 2176) {
                int och = idx / 34, ck = idx - och * 34;
                *(u16x8*)((unsigned short*)t1p + rbase + (size_t)och * TPL_ + ck * 8) = z;
            }
        }
    }
}

__global__ __launch_bounds__(256, 4) void k_ln1_conv1(const void* __restrict__ inp,
        const float* __restrict__ wsf, bf16* __restrict__ t1p,
        const int* __restrict__ flag)
{
    __shared__ short xsh[256 * 32];          // 16384 B
    __shared__ short osh[16 * OSTR1_];       // 8960 B
    if (*flag == 0) ln1_body<float>((const float*)inp, wsf, t1p, xsh, osh);
    else            ln1_body<bf16>((const bf16*)inp, wsf, t1p, xsh, osh);
}

// ------ DDF v9: LDS-staged t1 tile per cp + chp-fastest CWs (conflict-free staging) ------
// Per cp: cooperative coalesced load of the block's 2-plane 34x72 patch into Ts
// (9.8 KB), then compute reads LDS (structural-floor bank pattern). Kills the
// 3.4x redundant scattered 20-B global loads that made k_ddf latency-bound.
#define G_ 4
__global__ __launch_bounds__(256, 4) void k_ddf(const unsigned short* __restrict__ t1u,
        const float* __restrict__ cwfT, bf16* __restrict__ g, float* __restrict__ sums)
{
    __shared__ float CWs[4320];            // [tap*60+rr*10+cc][chp 8] = 17280 B
    __shared__ unsigned short Ts[4896];    // [ps 2][row 34][col 72] = 9792 B

    int bid = blockIdx.x;         // 1024
    int tile = bid & 31;
    int cg  = (bid >> 5) & 7;
    int b   = bid >> 8;
    int th = tile >> 2, tw = tile & 3;
    int cellh0 = th * 4;
    int cellw0 = tw * 8;
    int cp0 = cg * G_;

    {
        const float* cb = cwfT + (size_t)b * 589824;   // 1024*576
        for (int it = 0; it < 17; ++it) {
            int idx = it * 256 + threadIdx.x;          // 0..4319
            if (idx < 4320) {
                int chp  = idx & 7;
                int rest = idx >> 3;       // tap*60 + rr*10 + cc
                int cc  = rest % 10;
                int t3  = rest / 10;
                int rr  = t3 % 6;
                int tap = t3 / 6;
                int cr = cellh0 - 1 + rr; cr = cr < 0 ? 0 : (cr > 31 ? 31 : cr);
                int cw = cellw0 - 1 + cc; cw = cw < 0 ? 0 : (cw > 31 ? 31 : cw);
                CWs[rest * 8 + chp] =
                    cb[(size_t)(cr * 32 + cw) * 576 + tap * 64 + cg * 8 + chp];
            }
        }
    }

    int lane = threadIdx.x & 63, wid = threadIdx.x >> 6;
    int k = lane >> 3, r = lane & 7;
    int h0 = cellh0 * 8;
    int w0 = cellw0 * 8;
    int lrow = wid * 8 + r;              // 0..31 (lane's pixel row within tile)
    int h = h0 + lrow;
    int w = w0 + k * 8;

    int rsel = r >> 2;
    float fh = rsel ? ((float)r * 0.125f - 0.4375f) : ((float)r * 0.125f + 0.5625f);
    float gh = 1.f - fh;
    int rr0k = (wid + rsel) * 10 + k;

    const unsigned short* gbase = t1u + (size_t)(b * DW_) * TPL_ + (size_t)h0 * TRS_ + w0;
    bf16* gp = g + (size_t)(b * C_) * P_ + h * 256 + w;

    const float fwt[8] = {0.5625f, 0.6875f, 0.8125f, 0.9375f,
                          0.0625f, 0.1875f, 0.3125f, 0.4375f};

    for (int l = 0; l < G_; ++l) {
        int cp = cp0 + l;
        __syncthreads();   // previous compute done (and CWs staged, first iter)
        // ---- cooperative stage: 2 planes x 34 rows x 9 u16x8 chunks = 612 ----
        for (int it = 0; it < 3; ++it) {
            int idx = it * 256 + threadIdx.x;
            if (idx < 612) {
                int ps = idx >= 306 ? 1 : 0;
                int rem = idx - ps * 306;
                int row = rem / 9;
                int ck = rem - row * 9;
                const unsigned short* src = gbase + (size_t)(cp + ps * C_) * TPL_
                                            + row * TRS_ + ck * 8;
                *(u16x8*)(Ts + ps * 2448 + row * 72 + ck * 8) = *(const u16x8*)src;
            }
        }
        __syncthreads();

        float acc1[8], acc2[8];
        #pragma unroll
        for (int pass = 0; pass < 2; ++pass) {
            const unsigned short* pl = Ts + pass * 2448;
            float* acc = pass ? acc2 : acc1;
            int ch = pass ? (G_ + l) : l;

            u16x8 v8[3];
            unsigned int ve[3];
            #pragma unroll
            for (int i = 0; i < 3; ++i) {
                const unsigned short* rp = pl + (lrow + i) * 72 + k * 8;
                v8[i] = *(const u16x8*)rp;
                ve[i] = *(const unsigned int*)(rp + 8);
            }
            float S00[8], S01[8], S10[8], S11[8];
            #pragma unroll
            for (int c = 0; c < 8; ++c) { S00[c]=0.f; S01[c]=0.f; S10[c]=0.f; S11[c]=0.f; }
            #pragma unroll
            for (int i = 0; i < 3; ++i) {
                float p[10];
                #pragma unroll
                for (int j = 0; j < 8; ++j) p[j] = bfu((unsigned short)v8[i][j]);
                p[8] = bfu((unsigned short)(ve[i] & 0xFFFFu));
                p[9] = bfu((unsigned short)(ve[i] >> 16));
                #pragma unroll
                for (int j = 0; j < 3; ++j) {
                    const float* qb = CWs + ((i * 3 + j) * 60 + rr0k) * 8 + ch;
                    float w00 = qb[0],  w01 = qb[8],  w02 = qb[16];
                    float w10 = qb[80], w11 = qb[88], w12 = qb[96];
                    #pragma unroll
                    for (int c = 0; c < 8; ++c) {
                        float pv = p[c + j];
                        S00[c] += pv * ((c < 4) ? w00 : w01);
                        S01[c] += pv * ((c < 4) ? w01 : w02);
                        S10[c] += pv * ((c < 4) ? w10 : w11);
                        S11[c] += pv * ((c < 4) ? w11 : w12);
                    }
                }
            }
            #pragma unroll
            for (int c = 0; c < 8; ++c) {
                float fw = fwt[c], gw = 1.f - fw;
                acc[c] = gh * (gw * S00[c] + fw * S01[c]) + fh * (gw * S10[c] + fw * S11[c]);
            }
        }

        u16x8 ov;
        float s = 0.f;
        #pragma unroll
        for (int c = 0; c < 8; ++c) {
            float gv = acc1[c] * acc2[c];
            s += gv;
            bf16 bv = f2b(gv);
            ov[c] = *reinterpret_cast<unsigned short*>(&bv);
        }
        *(u16x8*)(gp + (size_t)cp * P_) = ov;

        #pragma unroll
        for (int off = 32; off >= 1; off >>= 1) s += __shfl_xor(s, off, 64);
        if (lane == 0) atomicAdd(&sums[b * C_ + cp], s);
    }
}

// ------- tail v3 (MFMA + fused SCA + LDS-transposed vector out-stores) -------
#define XSTR_ 32   // shorts per xsh row
#define ISTR_ 33   // floats per ipsh row
#define OSTRT_ 260 // floats per osh row (reuses ipsh storage; pad kills conflicts)

template<typename T>
__device__ __forceinline__ void tail_body(const T* __restrict__ inp,
        const bf16* __restrict__ g, const float* __restrict__ wsf,
        T* __restrict__ out, short* __restrict__ xsh, float* __restrict__ ipsh,
        float* __restrict__ svsh)
{
    const int t = threadIdx.x;
    const int b = blockIdx.x >> 8;
    const int p0 = (blockIdx.x & 255) << 8;

    // ---- fused SCA: svec = sca_w @ (sums/P) + sca_b (bit-identical to old k_sca) ----
    if (t < 32) {
        float acc = wsf[OBS + t];
        #pragma unroll
        for (int ch = 0; ch < C_; ++ch)
            acc += wsf[OWS + t * C_ + ch] * (wsf[OSUMS + b * C_ + ch] * (1.f / (float)P_));
        svsh[t] = acc;
    }
    __syncthreads();

    // ---- stage: x = g*svec (bf16) -> xsh[px][32]; inp (fp32) -> ipsh[px][33] ----
    {
        const unsigned short* gp = (const unsigned short*)g + (size_t)(b * C_) * P_ + p0 + t;
        unsigned short row[32];
        #pragma unroll
        for (int ch = 0; ch < C_; ++ch)
            row[ch] = fbits(bfu(gp[(size_t)ch * P_]) * svsh[ch]);
        u16x8* xr = (u16x8*)(xsh + t * XSTR_);
        #pragma unroll
        for (int qq = 0; qq < 4; ++qq) {
            u16x8 vv;
            #pragma unroll
            for (int j = 0; j < 8; ++j) vv[j] = row[qq * 8 + j];
            xr[qq] = vv;
        }
        const T* ip = inp + (size_t)(b * C_) * P_ + p0 + t;
        float* ir = ipsh + t * ISTR_;
        #pragma unroll
        for (int ch = 0; ch < C_; ++ch)
            ir[ch] = ldf<T>(ip + (size_t)ch * P_);
    }
    __syncthreads();

    const int lane = t & 63, wv = t >> 6;
    const int l15 = lane & 15, l4 = lane >> 4;
    const int wp0 = wv * 64;          // wave-private px range [wp0, wp0+64)

    s16x8 w3f[2], w4f[4];
    #pragma unroll
    for (int m = 0; m < 2; ++m) w3f[m] = wfrag8(wsf + OW3 + (m * 16 + l15) * 32 + l4 * 8);
    #pragma unroll
    for (int m = 0; m < 4; ++m) w4f[m] = wfrag8(wsf + OW4 + (m * 16 + l15) * 32 + l4 * 8);

    // ---- conv3 + beta residual -> y (fp32, 32 VGPR) ----
    f32x4 y[2][4];
    {
        f32x4 b3v[2], btv[2];
        #pragma unroll
        for (int m = 0; m < 2; ++m) {
            b3v[m] = *(const f32x4*)(wsf + OB3   + m * 16 + l4 * 4);
            btv[m] = *(const f32x4*)(wsf + OBETA + m * 16 + l4 * 4);
        }
        #pragma unroll
        for (int tn = 0; tn < 4; ++tn) {
            int px = wp0 + tn * 16 + l15;
            s16x8 xb = *(const s16x8*)(xsh + px * XSTR_ + l4 * 8);
            const float* irr = ipsh + px * ISTR_ + l4 * 4;
            #pragma unroll
            for (int m = 0; m < 2; ++m) {
                f32x4 acc = MF(w3f[m], xb, b3v[m]);   // bias-seeded
                f32x4 yy;
                #pragma unroll
                for (int i = 0; i < 4; ++i)
                    yy[i] = irr[m * 16 + i] + acc[i] * btv[m][i];
                y[m][tn] = yy;
            }
        }
    }
    // ipsh fully consumed; it becomes the output transpose buffer below
    __syncthreads();

    // ---- LN2 -> yn (bf16) written back over x region (wave-private rows) ----
    {
        f32x4 nwv[2], nbv[2];
        #pragma unroll
        for (int m = 0; m < 2; ++m) {
            nwv[m] = *(const f32x4*)(wsf + ON2W + m * 16 + l4 * 4);
            nbv[m] = *(const f32x4*)(wsf + ON2B + m * 16 + l4 * 4);
        }
        #pragma unroll
        for (int tn = 0; tn < 4; ++tn) {
            float s = 0.f;
            #pragma unroll
            for (int m = 0; m < 2; ++m)
                #pragma unroll
                for (int i = 0; i < 4; ++i) s += y[m][tn][i];
            s += __shfl_xor(s, 16);
            s += __shfl_xor(s, 32);
            float mean = s * (1.f / 32.f);
            float q = 0.f;
            #pragma unroll
            for (int m = 0; m < 2; ++m)
                #pragma unroll
                for (int i = 0; i < 4; ++i) { float d = y[m][tn][i] - mean; q += d * d; }
            q += __shfl_xor(q, 16);
            q += __shfl_xor(q, 32);
            float inv = rsqrtf(q * (1.f / 32.f) + 1e-6f);
            int px = wp0 + tn * 16 + l15;
            #pragma unroll
            for (int m = 0; m < 2; ++m) {
                us16x4 pk;
                #pragma unroll
                for (int i = 0; i < 4; ++i)
                    pk[i] = fbits((y[m][tn][i] - mean) * inv * nwv[m][i] + nbv[m][i]);
                *(us16x4*)(xsh + px * XSTR_ + m * 16 + l4 * 4) = pk;
            }
        }
    }

    // ---- conv4 (64ch) + SimpleGate -> u (bf16) over same rows ----
    {
        f32x4 b4v[4];
        #pragma unroll
        for (int m = 0; m < 4; ++m)
            b4v[m] = *(const f32x4*)(wsf + OB4 + m * 16 + l4 * 4);
        s16x8 yb[4];
        #pragma unroll
        for (int tn = 0; tn < 4; ++tn)
            yb[tn] = *(const s16x8*)(xsh + (wp0 + tn * 16 + l15) * XSTR_ + l4 * 8);
        #pragma unroll
        for (int tn = 0; tn < 4; ++tn) {
            f32x4 a4[4];
            #pragma unroll
            for (int m = 0; m < 4; ++m) a4[m] = MF(w4f[m], yb[tn], b4v[m]);
            int px = wp0 + tn * 16 + l15;
            #pragma unroll
            for (int m = 0; m < 2; ++m) {
                us16x4 pk;
                #pragma unroll
                for (int i = 0; i < 4; ++i) pk[i] = fbits(a4[m][i] * a4[m + 2][i]);
                *(us16x4*)(xsh + px * XSTR_ + m * 16 + l4 * 4) = pk;
            }
        }
    }

    // ---- conv5 + gamma residual -> osh (ipsh reuse), then vector writeback ----
    {
        s16x8 w5f[2];
        #pragma unroll
        for (int m = 0; m < 2; ++m) w5f[m] = wfrag8(wsf + OW5 + (m * 16 + l15) * 32 + l4 * 8);
        f32x4 b5v[2], gmv[2];
        #pragma unroll
        for (int m = 0; m < 2; ++m) {
            b5v[m] = *(const f32x4*)(wsf + OB5    + m * 16 + l4 * 4);
            gmv[m] = *(const f32x4*)(wsf + OGAMMA + m * 16 + l4 * 4);
        }
        s16x8 ub[4];
        #pragma unroll
        for (int tn = 0; tn < 4; ++tn)
            ub[tn] = *(const s16x8*)(xsh + (wp0 + tn * 16 + l15) * XSTR_ + l4 * 8);
        float* oshf = ipsh;   // [32 och][260 px-slots]
        #pragma unroll
        for (int tn = 0; tn < 4; ++tn) {
            int px = wp0 + tn * 16 + l15;
            #pragma unroll
            for (int m = 0; m < 2; ++m) {
                f32x4 acc = MF(w5f[m], ub[tn], b5v[m]);
                #pragma unroll
                for (int i = 0; i < 4; ++i)
                    oshf[(m * 16 + l4 * 4 + i) * OSTRT_ + px] = y[m][tn][i] + acc[i] * gmv[m][i];
            }
        }
    }
    __syncthreads();

    // writeback: 32 och rows x 256 px, aligned vector streams
    {
        const float* oshf = ipsh;
        if (dtag<T>::v == 0) {
            float* of = (float*)out;
            #pragma unroll
            for (int it = 0; it < 8; ++it) {
                int idx = it * 256 + t;          // 32*64 = 2048 float4 chunks
                int och = idx >> 6, ck = idx & 63;
                f32x4 v = *(const f32x4*)(oshf + och * OSTRT_ + ck * 4);
                *(f32x4*)(of + (size_t)(b * C_ + och) * P_ + p0 + ck * 4) = v;
            }
        } else {
            unsigned short* ob = (unsigned short*)out;
            #pragma unroll
            for (int it = 0; it < 4; ++it) {
                int idx = it * 256 + t;          // 32*32 = 1024 u16x8 chunks
                int och = idx >> 5, ck = idx & 31;
                f32x4 a = *(const f32x4*)(oshf + och * OSTRT_ + ck * 8);
                f32x4 c = *(const f32x4*)(oshf + och * OSTRT_ + ck * 8 + 4);
                u16x8 pk;
                pk[0] = fbits(a[0]); pk[1] = fbits(a[1]); pk[2] = fbits(a[2]); pk[3] = fbits(a[3]);
                pk[4] = fbits(c[0]); pk[5] = fbits(c[1]); pk[6] = fbits(c[2]); pk[7] = fbits(c[3]);
                *(u16x8*)(ob + (size_t)(b * C_ + och) * P_ + p0 + ck * 8) = pk;
            }
        }
    }
}

__global__ __launch_bounds__(256, 3) void k_tail(const void* __restrict__ inp,
        const bf16* __restrict__ g, const float* __restrict__ wsf,
        void* __restrict__ out, const int* __restrict__ flag)
{
    __shared__ short xsh[256 * XSTR_];   // 16384 B
    __shared__ float ipsh[256 * ISTR_];  // 33792 B (also output transpose buffer)
    __shared__ float svsh[32];
    if (*flag == 0) tail_body<float>((const float*)inp, g, wsf, (float*)out, xsh, ipsh, svsh);
    else            tail_body<bf16>((const bf16*)inp, g, wsf, (bf16*)out, xsh, ipsh, svsh);
}

extern "C" void kernel_launch(void* const* d_in, const int* in_sizes, int n_in,
                              void* d_out, int out_size, void* d_ws, size_t ws_size,
                              hipStream_t stream)
{
    float* wsf = (float*)d_ws;
    char* wsb = (char*)d_ws;
    float* cwf = (float*)(wsb + CWF_BOFF);
    bf16* t1p = (bf16*)(wsb + T1_BOFF);
    bf16* g   = (bf16*)(wsb + G_BOFF);
    int* flag = (int*)(wsf + OFLAG);

    k_detect<<<1, 64, 0, stream>>>((const unsigned short*)d_in[0], flag);

    int nblk = (B_ * P_) / 256;   // 1024

    k_prep<float><<<1, 256, 0, stream>>>(
        (const float*)d_in[2], (const float*)d_in[3], (const float*)d_in[4],
        (const float*)d_in[5], (const float*)d_in[6], (const float*)d_in[7],
        (const float*)d_in[8], (const float*)d_in[9], (const float*)d_in[10],
        (const float*)d_in[11], (const float*)d_in[12], (const float*)d_in[13],
        (const float*)d_in[14], (const float*)d_in[15], (const float*)d_in[16],
        (const float*)d_in[17], wsf, flag);
    k_prep<bf16><<<1, 256, 0, stream>>>(
        (const bf16*)d_in[2], (const bf16*)d_in[3], (const bf16*)d_in[4],
        (const bf16*)d_in[5], (const bf16*)d_in[6], (const bf16*)d_in[7],
        (const bf16*)d_in[8], (const bf16*)d_in[9], (const bf16*)d_in[10],
        (const bf16*)d_in[11], (const bf16*)d_in[12], (const bf16*)d_in[13],
        (const bf16*)d_in[14], (const bf16*)d_in[15], (const bf16*)d_in[16],
        (const bf16*)d_in[17], wsf, flag);

    k_cwf<<<576, 256, 0, stream>>>(d_in[1], cwf, flag);

    k_ln1_conv1<<<nblk, 256, 0, stream>>>(d_in[0], wsf, t1p, flag);

    k_ddf<<<1024, 256, 0, stream>>>((const unsigned short*)t1p, cwf, g, wsf + OSUMS);

    k_tail<<<nblk, 256, 0, stream>>>(d_in[0], g, wsf, d_out, flag);
}

// Round 13
// 229.251 us; speedup vs baseline: 1.0600x; 1.0600x over previous
//
#include <hip/hip_runtime.h>
#include <hip/hip_bf16.h>

typedef __hip_bfloat16 bf16;
typedef __attribute__((ext_vector_type(8))) unsigned short u16x8;
typedef __attribute__((ext_vector_type(8))) short s16x8;
typedef __attribute__((ext_vector_type(4))) float f32x4;
typedef __attribute__((ext_vector_type(4))) unsigned short us16x4;

#define B_   4
#define C_   32
#define DW_  64
#define H_   256
#define W_   256
#define P_   65536          // H_*W_
#define SRC_ 32             // source filter grid 32x32
#define TRS_ 272            // t1 padded row stride in shorts (544 B = 34*16, keeps 16B align)
#define TPL_ 70176          // padded plane shorts: 258 rows * 272

// ---- ws layout (float indices for the small stuff) ----
#define OW1    0            // 64*32
#define OB1    2048         // 64
#define OW3    2112         // 32*32
#define OB3    3136         // 32
#define OWS    3168         // 32*32 (sca)
#define OBS    4192         // 32
#define OW4    4224         // 64*32
#define OB4    6272         // 64
#define OW5    6336         // 32*32
#define OB5    7360         // 32
#define ON1W   7392
#define ON1B   7424
#define ON2W   7456
#define ON2B   7488
#define OBETA  7520
#define OGAMMA 7552
#define OSUMS  7584         // B_*C_ = 128
#define OSVEC  7712         // B_*C_ = 128 (unused now, kept for layout stability)
#define OFLAG  7900         // int flag: 0 = fp32 inputs, 1 = bf16 inputs
// byte offsets for big intermediates
#define CWF_BOFF 32768ull                        // cwfT fp32: 4*1024*576*4 = 9437184 B
#define T1_BOFF  (CWF_BOFF + 9437184ull)         // t1 padded bf16: 256*70176*2 = 35930112 B
#define G_BOFF   (T1_BOFF + 35930112ull)         // g bf16: 16777216 B
// total ws ~= 62.2 MB

__device__ __forceinline__ bf16  f2b(float v){ return __float2bfloat16(v); }
__device__ __forceinline__ float bfu(unsigned short u){ return __uint_as_float(((unsigned int)u) << 16); }
__device__ __forceinline__ unsigned short fbits(float v){
    bf16 b = __float2bfloat16(v);
    return *reinterpret_cast<unsigned short*>(&b);
}

template<typename T> __device__ __forceinline__ float ldf(const T* p);
template<> __device__ __forceinline__ float ldf<float>(const float* p){ return *p; }
template<> __device__ __forceinline__ float ldf<bf16>(const bf16* p){ return __bfloat162float(*p); }

template<typename T> struct dtag;
template<> struct dtag<float>{ static constexpr int v = 0; };
template<> struct dtag<bf16>{ static constexpr int v = 1; };

__device__ __forceinline__ f32x4 MF(s16x8 a, s16x8 b, f32x4 c){
    return __builtin_amdgcn_mfma_f32_16x16x32_bf16(a, b, c, 0, 0, 0);
}
// 8 consecutive fp32 weights -> bf16x8 fragment
__device__ __forceinline__ s16x8 wfrag8(const float* p){
    float4 a = *(const float4*)p;
    float4 c = *(const float4*)(p + 4);
    s16x8 r;
    r[0] = (short)fbits(a.x); r[1] = (short)fbits(a.y);
    r[2] = (short)fbits(a.z); r[3] = (short)fbits(a.w);
    r[4] = (short)fbits(c.x); r[5] = (short)fbits(c.y);
    r[6] = (short)fbits(c.z); r[7] = (short)fbits(c.w);
    return r;
}

// ---------------- dtype detector (fp32 low-mantissa halves decode huge/NaN) ----------------
__global__ void k_detect(const unsigned short* __restrict__ raw, int* __restrict__ flag)
{
    int t = threadIdx.x;  // 64 threads
    int bad = 0;
    for (int k = 0; k < 8; ++k) {
        unsigned short u = raw[2 * (t + 64 * k)];
        float v = __uint_as_float(((unsigned int)u) << 16);
        if (!(fabsf(v) < 1e6f)) bad = 1;
    }
    int anybad = __any(bad);
    if (t == 0) *flag = anybad ? 0 : 1;
}

// ---------------- weights -> fp32 in ws, zero SCA sums (1 block; args are device ptrs) ----------------
template<typename T>
__global__ void k_prep(const T* __restrict__ w1, const T* __restrict__ b1,
                       const T* __restrict__ w3, const T* __restrict__ b3,
                       const T* __restrict__ wsc, const T* __restrict__ bsc_,
                       const T* __restrict__ w4, const T* __restrict__ b4,
                       const T* __restrict__ w5, const T* __restrict__ b5,
                       const T* __restrict__ n1w, const T* __restrict__ n1b,
                       const T* __restrict__ n2w, const T* __restrict__ n2b,
                       const T* __restrict__ bet, const T* __restrict__ gam,
                       float* __restrict__ wsf, const int* __restrict__ flag)
{
    if (*flag != dtag<T>::v) return;
    int t = threadIdx.x;
    for (int i = t; i < 2048; i += 256) wsf[OW1 + i] = ldf<T>(w1 + i);
    for (int i = t; i < 64;   i += 256) wsf[OB1 + i] = ldf<T>(b1 + i);
    for (int i = t; i < 1024; i += 256) wsf[OW3 + i] = ldf<T>(w3 + i);
    for (int i = t; i < 32;   i += 256) wsf[OB3 + i] = ldf<T>(b3 + i);
    for (int i = t; i < 1024; i += 256) wsf[OWS + i] = ldf<T>(wsc + i);
    for (int i = t; i < 32;   i += 256) wsf[OBS + i] = ldf<T>(bsc_ + i);
    for (int i = t; i < 2048; i += 256) wsf[OW4 + i] = ldf<T>(w4 + i);
    for (int i = t; i < 64;   i += 256) wsf[OB4 + i] = ldf<T>(b4 + i);
    for (int i = t; i < 1024; i += 256) wsf[OW5 + i] = ldf<T>(w5 + i);
    for (int i = t; i < 32;   i += 256) wsf[OB5 + i] = ldf<T>(b5 + i);
    for (int i = t; i < 32;   i += 256) wsf[ON1W + i] = ldf<T>(n1w + i);
    for (int i = t; i < 32;   i += 256) wsf[ON1B + i] = ldf<T>(n1b + i);
    for (int i = t; i < 32;   i += 256) wsf[ON2W + i] = ldf<T>(n2w + i);
    for (int i = t; i < 32;   i += 256) wsf[ON2B + i] = ldf<T>(n2b + i);
    for (int i = t; i < 32;   i += 256) wsf[OBETA + i] = ldf<T>(bet + i);
    for (int i = t; i < 32;   i += 256) wsf[OGAMMA + i] = ldf<T>(gam + i);
    for (int i = t; i < 128;  i += 256) wsf[OSUMS + i] = 0.f;
}

// ------- cwf body: cw2 -> cwfT[b][rc][tap][p] via LDS-tiled transpose -------
// p = [cg 3][chq 1][ch4 2] bits; oc = chq*32 + cg*4 + ch4.
// 576 sub-blocks: b(4) x tap(9) x rct(16). Both global sides coalesced.
__device__ void cwf_body(const void* __restrict__ cw, float* __restrict__ cwfT,
                         int fl, int blk, float (*tile)[65])
{
    int rct = blk & 15;
    int tap = (blk >> 4) % 9;
    int b   = blk / 144;
    int rc0 = rct * 64;
    int tl  = threadIdx.x & 63;
    int tg  = threadIdx.x >> 6;
    #pragma unroll
    for (int it = 0; it < 16; ++it) {
        int oc = it * 4 + tg;
        size_t iidx = ((size_t)(b * DW_ + oc) * 9 + tap) * 1024 + rc0 + tl;
        tile[oc][tl] = (fl == 0) ? ((const float*)cw)[iidx]
                                 : bfu(((const unsigned short*)cw)[iidx]);
    }
    __syncthreads();
    #pragma unroll
    for (int it = 0; it < 16; ++it) {
        int rcl = it * 4 + tg;
        int p = tl;
        int oc = ((p >> 2) & 1) * 32 + (p >> 3) * 4 + (p & 3);
        cwfT[((size_t)(b * 1024 + rc0 + rcl) * 9 + tap) * 64 + p] = tile[oc][rcl];
    }
}

// ------- LN1 + conv1 (MFMA + LDS-transposed full-row stores) -------
#define OSTR1_ 280
template<typename T>
__device__ __forceinline__ void ln1_body(const T* __restrict__ inp,
        const float* __restrict__ wsf, bf16* __restrict__ t1p,
        short* __restrict__ xsh, short* __restrict__ osh, int blk)
{
    const int t = threadIdx.x;
    const int b = blk >> 8;
    const int h = blk & 255;
    const int p0 = h << 8;

    {
        const T* ip = inp + (size_t)(b * C_) * P_ + p0 + t;
        float v[C_];
        float m = 0.f;
        #pragma unroll
        for (int ch = 0; ch < C_; ++ch) { v[ch] = ldf<T>(ip + (size_t)ch * P_); m += v[ch]; }
        m *= (1.f / C_);
        float var = 0.f;
        #pragma unroll
        for (int ch = 0; ch < C_; ++ch) { float d = v[ch] - m; var += d * d; }
        var *= (1.f / C_);
        float inv = rsqrtf(var + 1e-6f);
        u16x8* xr = (u16x8*)(xsh + t * 32);
        #pragma unroll
        for (int qq = 0; qq < 4; ++qq) {
            u16x8 vv;
            #pragma unroll
            for (int j = 0; j < 8; ++j) {
                int ch = qq * 8 + j;
                vv[j] = fbits((v[ch] - m) * inv * wsf[ON1W + ch] + wsf[ON1B + ch]);
            }
            xr[qq] = vv;
        }
        int och = t >> 4, cc = t & 15;
        osh[och * OSTR1_ + (cc == 0 ? 0 : 256 + cc)] = 0;
    }
    __syncthreads();

    const int lane = t & 63, wv = t >> 6;
    const int l15 = lane & 15, l4 = lane >> 4;
    const int wp0 = wv * 64;

    s16x8 w1f[4];
    f32x4 b1v[4];
    #pragma unroll
    for (int m = 0; m < 4; ++m) {
        w1f[m] = wfrag8(wsf + OW1 + (m * 16 + l15) * 32 + l4 * 8);
        b1v[m] = *(const f32x4*)(wsf + OB1 + m * 16 + l4 * 4);
    }
    s16x8 xb[4];
    #pragma unroll
    for (int tn = 0; tn < 4; ++tn)
        xb[tn] = *(const s16x8*)(xsh + (wp0 + tn * 16 + l15) * 32 + l4 * 8);

    const size_t prow = (size_t)(b * DW_) * TPL_ + (size_t)(h + 1) * TRS_;
    #pragma unroll
    for (int m = 0; m < 4; ++m) {
        #pragma unroll
        for (int tn = 0; tn < 4; ++tn) {
            f32x4 acc = MF(w1f[m], xb[tn], b1v[m]);
            int px = wp0 + tn * 16 + l15;
            #pragma unroll
            for (int i = 0; i < 4; ++i)
                osh[(l4 * 4 + i) * OSTR1_ + 1 + px] = (short)fbits(acc[i]);
        }
        __syncthreads();
        for (int it = 0; it < 3; ++it) {
            int idx = it * 256 + t;
            if (idx < 544) {
                int och = idx / 34, ck = idx - och * 34;
                u16x8 v = *(const u16x8*)(osh + och * OSTR1_ + ck * 8);
                *(u16x8*)((unsigned short*)t1p + prow + (size_t)(m * 16 + och) * TPL_ + ck * 8) = v;
            }
        }
        __syncthreads();
    }

    if (h == 0 || h == 255) {
        size_t rbase = (size_t)(b * DW_) * TPL_ + (h == 0 ? 0 : (size_t)257 * TRS_);
        u16x8 z;
        #pragma unroll
        for (int j = 0; j < 8; ++j) z[j] = 0;
        for (int it = 0; it < 9; ++it) {
            int idx = it * 256 + t;
            if (idx < 2176) {
                int och = idx / 34, ck = idx - och * 34;
                *(u16x8*)((unsigned short*)t1p + rbase + (size_t)och * TPL_ + ck * 8) = z;
            }
        }
    }
}

// ------- merged front kernel: blocks 0..1023 = ln1, 1024..1599 = cwf -------
// (prep runs as its own prior launch — stream order makes wsf ready for ln1)
__global__ __launch_bounds__(256, 4) void k_front(const void* __restrict__ inp,
        const void* __restrict__ cw, float* __restrict__ wsf,
        float* __restrict__ cwfT, bf16* __restrict__ t1p,
        const int* __restrict__ flag)
{
    __shared__ char smem[25344];   // max(ln1: 16384+8960, cwf: 16640)
    int bid = blockIdx.x;
    int fl = *flag;
    if (bid < 1024) {
        short* xsh = (short*)smem;               // 16384 B
        short* osh = (short*)(smem + 16384);     // 8960 B
        if (fl == 0) ln1_body<float>((const float*)inp, wsf, t1p, xsh, osh, bid);
        else         ln1_body<bf16>((const bf16*)inp, wsf, t1p, xsh, osh, bid);
    } else {
        cwf_body(cw, cwfT, fl, bid - 1024, (float(*)[65])smem);
    }
}

// ------ DDF v8 (exact R10 form — proven 68.2 us, FETCH 59 MB, WRITE 30 MB) ------
// R7 compute loop + tiled-layout staging from cwfT.
#define G_ 4
__global__ __launch_bounds__(256, 4) void k_ddf(const unsigned short* __restrict__ t1u,
        const float* __restrict__ cwfT, bf16* __restrict__ g, float* __restrict__ sums)
{
    __shared__ float CWs[4320];   // [chp 8][tap 9][rr 6][cc 10] = 17280 B

    int bid = blockIdx.x;         // 1024
    int tile = bid & 31;          // 8 row-tiles x 4 col-tiles
    int cg  = (bid >> 5) & 7;     // 8 cp-groups of G_=4
    int b   = bid >> 8;           // 4
    int th = tile >> 2, tw = tile & 3;
    int cellh0 = th * 4;          // 4 cell rows per block
    int cellw0 = tw * 8;          // 8 cell cols per block
    int cp0 = cg * G_;

    {
        const float* cb = cwfT + (size_t)b * 589824;   // 1024*576
        for (int it = 0; it < 17; ++it) {
            int idx = it * 256 + threadIdx.x;          // 0..4319
            if (idx < 4320) {
                int chp = idx & 7;
                int t2  = idx >> 3;     // 0..539
                int tap = t2 % 9;
                int t3  = t2 / 9;       // 0..59
                int cc  = t3 % 10;
                int rr  = t3 / 10;      // 0..5
                int cr = cellh0 - 1 + rr; cr = cr < 0 ? 0 : (cr > 31 ? 31 : cr);
                int cw = cellw0 - 1 + cc; cw = cw < 0 ? 0 : (cw > 31 ? 31 : cw);
                CWs[chp * 540 + tap * 60 + rr * 10 + cc] =
                    cb[(size_t)(cr * 32 + cw) * 576 + tap * 64 + cg * 8 + chp];
            }
        }
    }
    __syncthreads();

    int lane = threadIdx.x & 63, wid = threadIdx.x >> 6;
    int k = lane >> 3, r = lane & 7;
    int cellh = cellh0 + wid;
    int h = cellh * 8 + r;
    int w = (cellw0 + k) * 8;

    int rsel = r >> 2;
    float fh = rsel ? ((float)r * 0.125f - 0.4375f) : ((float)r * 0.125f + 0.5625f);
    float gh = 1.f - fh;
    int rr0k = (wid + rsel) * 10 + k;

    const unsigned short* tb = t1u + (size_t)(b * DW_) * TPL_ + (size_t)h * TRS_ + w;
    bf16* gp = g + (size_t)(b * C_) * P_ + h * 256 + w;

    for (int l = 0; l < G_; ++l) {
        int cp = cp0 + l;
        const unsigned short* pl1 = tb + (size_t)cp * TPL_;
        const unsigned short* pl2 = pl1 + (size_t)C_ * TPL_;
        const float* q1 = CWs + l * 540;
        const float* q2 = CWs + (G_ + l) * 540;

        float acc1[8], acc2[8];
        #pragma unroll
        for (int pass = 0; pass < 2; ++pass) {
            const unsigned short* pl = pass ? pl2 : pl1;
            const float* q = pass ? q2 : q1;
            float* acc = pass ? acc2 : acc1;

            u16x8 v8[3];
            unsigned int ve[3];
            #pragma unroll
            for (int i = 0; i < 3; ++i) {
                const unsigned short* rp = pl + i * TRS_;
                v8[i] = *(const u16x8*)rp;
                ve[i] = *(const unsigned int*)(rp + 8);
            }
            float S00[8], S01[8], S10[8], S11[8];
            #pragma unroll
            for (int c = 0; c < 8; ++c) { S00[c]=0.f; S01[c]=0.f; S10[c]=0.f; S11[c]=0.f; }
            #pragma unroll
            for (int i = 0; i < 3; ++i) {
                float p[10];
                #pragma unroll
                for (int j = 0; j < 8; ++j) p[j] = bfu((unsigned short)v8[i][j]);
                p[8] = bfu((unsigned short)(ve[i] & 0xFFFFu));
                p[9] = bfu((unsigned short)(ve[i] >> 16));
                #pragma unroll
                for (int j = 0; j < 3; ++j) {
                    const float* qb = q + (i * 3 + j) * 60 + rr0k;
                    float w00 = qb[0],  w01 = qb[1],  w02 = qb[2];
                    float w10 = qb[10], w11 = qb[11], w12 = qb[12];
                    #pragma unroll
                    for (int c = 0; c < 8; ++c) {
                        float pv = p[c + j];
                        S00[c] += pv * ((c < 4) ? w00 : w01);
                        S01[c] += pv * ((c < 4) ? w01 : w02);
                        S10[c] += pv * ((c < 4) ? w10 : w11);
                        S11[c] += pv * ((c < 4) ? w11 : w12);
                    }
                }
            }
            const float fwt[8] = {0.5625f, 0.6875f, 0.8125f, 0.9375f,
                                  0.0625f, 0.1875f, 0.3125f, 0.4375f};
            #pragma unroll
            for (int c = 0; c < 8; ++c) {
                float fw = fwt[c], gw = 1.f - fw;
                acc[c] = gh * (gw * S00[c] + fw * S01[c]) + fh * (gw * S10[c] + fw * S11[c]);
            }
        }

        u16x8 ov;
        float s = 0.f;
        #pragma unroll
        for (int c = 0; c < 8; ++c) {
            float gv = acc1[c] * acc2[c];
            s += gv;
            bf16 bv = f2b(gv);
            ov[c] = *reinterpret_cast<unsigned short*>(&bv);
        }
        *(u16x8*)(gp + (size_t)cp * P_) = ov;

        #pragma unroll
        for (int off = 32; off >= 1; off >>= 1) s += __shfl_xor(s, off, 64);
        if (lane == 0) atomicAdd(&sums[b * C_ + cp], s);
    }
}

// ------- tail (MFMA + fused SCA + LDS-transposed vector out-stores) -------
#define XSTR_ 32   // shorts per xsh row
#define ISTR_ 33   // floats per ipsh row
#define OSTRT_ 260 // floats per osh row (reuses ipsh storage; pad kills conflicts)

template<typename T>
__device__ __forceinline__ void tail_body(const T* __restrict__ inp,
        const bf16* __restrict__ g, const float* __restrict__ wsf,
        T* __restrict__ out, short* __restrict__ xsh, float* __restrict__ ipsh,
        float* __restrict__ svsh)
{
    const int t = threadIdx.x;
    const int b = blockIdx.x >> 8;
    const int p0 = (blockIdx.x & 255) << 8;

    // ---- fused SCA: svec = sca_w @ (sums/P) + sca_b ----
    if (t < 32) {
        float acc = wsf[OBS + t];
        #pragma unroll
        for (int ch = 0; ch < C_; ++ch)
            acc += wsf[OWS + t * C_ + ch] * (wsf[OSUMS + b * C_ + ch] * (1.f / (float)P_));
        svsh[t] = acc;
    }
    __syncthreads();

    // ---- stage: x = g*svec (bf16) -> xsh[px][32]; inp (fp32) -> ipsh[px][33] ----
    {
        const unsigned short* gp = (const unsigned short*)g + (size_t)(b * C_) * P_ + p0 + t;
        unsigned short row[32];
        #pragma unroll
        for (int ch = 0; ch < C_; ++ch)
            row[ch] = fbits(bfu(gp[(size_t)ch * P_]) * svsh[ch]);
        u16x8* xr = (u16x8*)(xsh + t * XSTR_);
        #pragma unroll
        for (int qq = 0; qq < 4; ++qq) {
            u16x8 vv;
            #pragma unroll
            for (int j = 0; j < 8; ++j) vv[j] = row[qq * 8 + j];
            xr[qq] = vv;
        }
        const T* ip = inp + (size_t)(b * C_) * P_ + p0 + t;
        float* ir = ipsh + t * ISTR_;
        #pragma unroll
        for (int ch = 0; ch < C_; ++ch)
            ir[ch] = ldf<T>(ip + (size_t)ch * P_);
    }
    __syncthreads();

    const int lane = t & 63, wv = t >> 6;
    const int l15 = lane & 15, l4 = lane >> 4;
    const int wp0 = wv * 64;          // wave-private px range [wp0, wp0+64)

    s16x8 w3f[2], w4f[4];
    #pragma unroll
    for (int m = 0; m < 2; ++m) w3f[m] = wfrag8(wsf + OW3 + (m * 16 + l15) * 32 + l4 * 8);
    #pragma unroll
    for (int m = 0; m < 4; ++m) w4f[m] = wfrag8(wsf + OW4 + (m * 16 + l15) * 32 + l4 * 8);

    // ---- conv3 + beta residual -> y (fp32, 32 VGPR) ----
    f32x4 y[2][4];
    {
        f32x4 b3v[2], btv[2];
        #pragma unroll
        for (int m = 0; m < 2; ++m) {
            b3v[m] = *(const f32x4*)(wsf + OB3   + m * 16 + l4 * 4);
            btv[m] = *(const f32x4*)(wsf + OBETA + m * 16 + l4 * 4);
        }
        #pragma unroll
        for (int tn = 0; tn < 4; ++tn) {
            int px = wp0 + tn * 16 + l15;
            s16x8 xb = *(const s16x8*)(xsh + px * XSTR_ + l4 * 8);
            const float* irr = ipsh + px * ISTR_ + l4 * 4;
            #pragma unroll
            for (int m = 0; m < 2; ++m) {
                f32x4 acc = MF(w3f[m], xb, b3v[m]);   // bias-seeded
                f32x4 yy;
                #pragma unroll
                for (int i = 0; i < 4; ++i)
                    yy[i] = irr[m * 16 + i] + acc[i] * btv[m][i];
                y[m][tn] = yy;
            }
        }
    }
    // ipsh fully consumed; it becomes the output transpose buffer below
    __syncthreads();

    // ---- LN2 -> yn (bf16) written back over x region (wave-private rows) ----
    {
        f32x4 nwv[2], nbv[2];
        #pragma unroll
        for (int m = 0; m < 2; ++m) {
            nwv[m] = *(const f32x4*)(wsf + ON2W + m * 16 + l4 * 4);
            nbv[m] = *(const f32x4*)(wsf + ON2B + m * 16 + l4 * 4);
        }
        #pragma unroll
        for (int tn = 0; tn < 4; ++tn) {
            float s = 0.f;
            #pragma unroll
            for (int m = 0; m < 2; ++m)
                #pragma unroll
                for (int i = 0; i < 4; ++i) s += y[m][tn][i];
            s += __shfl_xor(s, 16);
            s += __shfl_xor(s, 32);
            float mean = s * (1.f / 32.f);
            float q = 0.f;
            #pragma unroll
            for (int m = 0; m < 2; ++m)
                #pragma unroll
                for (int i = 0; i < 4; ++i) { float d = y[m][tn][i] - mean; q += d * d; }
            q += __shfl_xor(q, 16);
            q += __shfl_xor(q, 32);
            float inv = rsqrtf(q * (1.f / 32.f) + 1e-6f);
            int px = wp0 + tn * 16 + l15;
            #pragma unroll
            for (int m = 0; m < 2; ++m) {
                us16x4 pk;
                #pragma unroll
                for (int i = 0; i < 4; ++i)
                    pk[i] = fbits((y[m][tn][i] - mean) * inv * nwv[m][i] + nbv[m][i]);
                *(us16x4*)(xsh + px * XSTR_ + m * 16 + l4 * 4) = pk;
            }
        }
    }

    // ---- conv4 (64ch) + SimpleGate -> u (bf16) over same rows ----
    {
        f32x4 b4v[4];
        #pragma unroll
        for (int m = 0; m < 4; ++m)
            b4v[m] = *(const f32x4*)(wsf + OB4 + m * 16 + l4 * 4);
        s16x8 yb[4];
        #pragma unroll
        for (int tn = 0; tn < 4; ++tn)
            yb[tn] = *(const s16x8*)(xsh + (wp0 + tn * 16 + l15) * XSTR_ + l4 * 8);
        #pragma unroll
        for (int tn = 0; tn < 4; ++tn) {
            f32x4 a4[4];
            #pragma unroll
            for (int m = 0; m < 4; ++m) a4[m] = MF(w4f[m], yb[tn], b4v[m]);
            int px = wp0 + tn * 16 + l15;
            #pragma unroll
            for (int m = 0; m < 2; ++m) {
                us16x4 pk;
                #pragma unroll
                for (int i = 0; i < 4; ++i) pk[i] = fbits(a4[m][i] * a4[m + 2][i]);
                *(us16x4*)(xsh + px * XSTR_ + m * 16 + l4 * 4) = pk;
            }
        }
    }

    // ---- conv5 + gamma residual -> osh (ipsh reuse), then vector writeback ----
    {
        s16x8 w5f[2];
        #pragma unroll
        for (int m = 0; m < 2; ++m) w5f[m] = wfrag8(wsf + OW5 + (m * 16 + l15) * 32 + l4 * 8);
        f32x4 b5v[2], gmv[2];
        #pragma unroll
        for (int m = 0; m < 2; ++m) {
            b5v[m] = *(const f32x4*)(wsf + OB5    + m * 16 + l4 * 4);
            gmv[m] = *(const f32x4*)(wsf + OGAMMA + m * 16 + l4 * 4);
        }
        s16x8 ub[4];
        #pragma unroll
        for (int tn = 0; tn < 4; ++tn)
            ub[tn] = *(const s16x8*)(xsh + (wp0 + tn * 16 + l15) * XSTR_ + l4 * 8);
        float* oshf = ipsh;   // [32 och][260 px-slots]
        #pragma unroll
        for (int tn = 0; tn < 4; ++tn) {
            int px = wp0 + tn * 16 + l15;
            #pragma unroll
            for (int m = 0; m < 2; ++m) {
                f32x4 acc = MF(w5f[m], ub[tn], b5v[m]);
                #pragma unroll
                for (int i = 0; i < 4; ++i)
                    oshf[(m * 16 + l4 * 4 + i) * OSTRT_ + px] = y[m][tn][i] + acc[i] * gmv[m][i];
            }
        }
    }
    __syncthreads();

    // writeback: 32 och rows x 256 px, aligned vector streams
    {
        const float* oshf = ipsh;
        if (dtag<T>::v == 0) {
            float* of = (float*)out;
            #pragma unroll
            for (int it = 0; it < 8; ++it) {
                int idx = it * 256 + t;          // 32*64 = 2048 float4 chunks
                int och = idx >> 6, ck = idx & 63;
                f32x4 v = *(const f32x4*)(oshf + och * OSTRT_ + ck * 4);
                *(f32x4*)(of + (size_t)(b * C_ + och) * P_ + p0 + ck * 4) = v;
            }
        } else {
            unsigned short* ob = (unsigned short*)out;
            #pragma unroll
            for (int it = 0; it < 4; ++it) {
                int idx = it * 256 + t;          // 32*32 = 1024 u16x8 chunks
                int och = idx >> 5, ck = idx & 31;
                f32x4 a = *(const f32x4*)(oshf + och * OSTRT_ + ck * 8);
                f32x4 c = *(const f32x4*)(oshf + och * OSTRT_ + ck * 8 + 4);
                u16x8 pk;
                pk[0] = fbits(a[0]); pk[1] = fbits(a[1]); pk[2] = fbits(a[2]); pk[3] = fbits(a[3]);
                pk[4] = fbits(c[0]); pk[5] = fbits(c[1]); pk[6] = fbits(c[2]); pk[7] = fbits(c[3]);
                *(u16x8*)(ob + (size_t)(b * C_ + och) * P_ + p0 + ck * 8) = pk;
            }
        }
    }
}

__global__ __launch_bounds__(256, 3) void k_tail(const void* __restrict__ inp,
        const bf16* __restrict__ g, const float* __restrict__ wsf,
        void* __restrict__ out, const int* __restrict__ flag)
{
    __shared__ short xsh[256 * XSTR_];   // 16384 B
    __shared__ float ipsh[256 * ISTR_];  // 33792 B (also output transpose buffer)
    __shared__ float svsh[32];
    if (*flag == 0) tail_body<float>((const float*)inp, g, wsf, (float*)out, xsh, ipsh, svsh);
    else            tail_body<bf16>((const bf16*)inp, g, wsf, (bf16*)out, xsh, ipsh, svsh);
}

extern "C" void kernel_launch(void* const* d_in, const int* in_sizes, int n_in,
                              void* d_out, int out_size, void* d_ws, size_t ws_size,
                              hipStream_t stream)
{
    float* wsf = (float*)d_ws;
    char* wsb = (char*)d_ws;
    float* cwf = (float*)(wsb + CWF_BOFF);
    bf16* t1p = (bf16*)(wsb + T1_BOFF);
    bf16* g   = (bf16*)(wsb + G_BOFF);
    int* flag = (int*)(wsf + OFLAG);

    k_detect<<<1, 64, 0, stream>>>((const unsigned short*)d_in[0], flag);

    k_prep<float><<<1, 256, 0, stream>>>(
        (const float*)d_in[2], (const float*)d_in[3], (const float*)d_in[4],
        (const float*)d_in[5], (const float*)d_in[6], (const float*)d_in[7],
        (const float*)d_in[8], (const float*)d_in[9], (const float*)d_in[10],
        (const float*)d_in[11], (const float*)d_in[12], (const float*)d_in[13],
        (const float*)d_in[14], (const float*)d_in[15], (const float*)d_in[16],
        (const float*)d_in[17], wsf, flag);
    k_prep<bf16><<<1, 256, 0, stream>>>(
        (const bf16*)d_in[2], (const bf16*)d_in[3], (const bf16*)d_in[4],
        (const bf16*)d_in[5], (const bf16*)d_in[6], (const bf16*)d_in[7],
        (const bf16*)d_in[8], (const bf16*)d_in[9], (const bf16*)d_in[10],
        (const bf16*)d_in[11], (const bf16*)d_in[12], (const bf16*)d_in[13],
        (const bf16*)d_in[14], (const bf16*)d_in[15], (const bf16*)d_in[16],
        (const bf16*)d_in[17], wsf, flag);

    k_front<<<1600, 256, 0, stream>>>(d_in[0], d_in[1], wsf, cwf, t1p, flag);

    k_ddf<<<1024, 256, 0, stream>>>((const unsigned short*)t1p, cwf, g, wsf + OSUMS);

    k_tail<<<1024, 256, 0, stream>>>(d_in[0], g, wsf, d_out, flag);
}